// Round 2
// baseline (176002.332 us; speedup 1.0000x reference)
//
#include <hip/hip_runtime.h>
#include <hip/hip_fp16.h>

// Problem dims
#define TT 512
#define BB 64
#define MM 512
#define DXD 384
#define HH 192
#define AA 192
#define NWG 256    // (dir, b, half) for P1; (dir, j) for P2/P3

// ---------------- fast math ----------------
__device__ __forceinline__ float fast_sigmoid(float x) {
  float e = __expf(-x);
  return __builtin_amdgcn_rcpf(1.f + e);
}
__device__ __forceinline__ float fast_tanh(float x) {
  float e = __expf(2.f * x);
  return 1.f - 2.f * __builtin_amdgcn_rcpf(e + 1.f);
}
__device__ __forceinline__ float2 h2f2(unsigned u) {
  __half2 h = *reinterpret_cast<__half2*>(&u);
  return __half22float2(h);
}

// ---------------- grid barrier (256 WGs, 1/CU, co-resident) ----------------
__device__ __forceinline__ void grid_barrier(unsigned* bar, unsigned target) {
  __threadfence();
  __syncthreads();
  if (threadIdx.x == 0) {
    __hip_atomic_fetch_add(bar, 1u, __ATOMIC_RELAXED, __HIP_MEMORY_SCOPE_AGENT);
    while (__hip_atomic_load(bar, __ATOMIC_RELAXED, __HIP_MEMORY_SCOPE_AGENT) < target) {
      __builtin_amdgcn_s_sleep(2);
    }
  }
  __syncthreads();
  __threadfence();
}

// ---------------- precompute: C[r,0:192] = X[srcrow(r),0:384] @ W[384,192], fp16 out ----------------
struct ProjParams {
  const float* X[4]; const float* W[4]; __half* C[4]; int rev[4];
};

__global__ __launch_bounds__(192) void proj_kernel(ProjParams pp) {
  __shared__ float xs[32 * 384];
  const int job = blockIdx.y;
  const float* __restrict__ X = pp.X[job];
  const float* __restrict__ W = pp.W[job];
  __half* __restrict__ C = pp.C[job];
  const int rev = pp.rev[job];
  const int r0 = blockIdx.x * 32;
  const int tid = threadIdx.x;

  for (int idx = tid; idx < 32 * 384; idx += 192) {
    int r = idx / 384, k = idx - r * 384;
    int row = r0 + r;
    int srow = row;
    if (rev) { int t = row >> 6, b2 = row & 63; srow = ((TT - 1 - t) << 6) | b2; }
    xs[idx] = X[(size_t)srow * 384 + k];
  }
  __syncthreads();

  float acc[32];
  #pragma unroll
  for (int r = 0; r < 32; ++r) acc[r] = 0.f;
  for (int k = 0; k < 384; ++k) {
    float w = W[k * 192 + tid];
    #pragma unroll
    for (int r = 0; r < 32; ++r) acc[r] = fmaf(xs[r * 384 + k], w, acc[r]);
  }
  #pragma unroll
  for (int r = 0; r < 32; ++r) C[(size_t)(r0 + r) * 192 + tid] = __float2half(acc[r]);
}

// ---------------- memory transpose+cvt: mem_t[b][m][d] = (half)memory[m][b][d] ----------------
__global__ __launch_bounds__(384) void memcvt_kernel(const float* __restrict__ src,
                                                     __half* __restrict__ dst) {
  int m = blockIdx.x, b = blockIdx.y, d = threadIdx.x;
  dst[((size_t)b * MM + m) * 384 + d] = __float2half(src[((size_t)m * 64 + b) * 384 + d]);
}

// ---------------- dynamic LDS layout (bytes) ----------------
#define L_MP    0                 // 256*192 halfs = 98304
#define L_OVL   98304             // overlay: xcs [64][67]f / redp [8][384]f
#define L_WCS   (98304 + 17152)   // [64][8] f = 2048
#define L_GIS   (98304 + 19200)   // [64][6] f = 1536
#define L_GHS   (98304 + 20736)   // [64][6] f = 1536
#define L_Q     120832            // 192 f
#define L_QP    121600            // 384 f
#define L_HS    123136            // 192 f
#define L_VS    123904            // 192 f
#define L_IZ    124672            // 64 f
#define L_ZP    124928            // 8 f (pad 256)
#define SCAN_LDS 125184
static_assert(SCAN_LDS <= 160 * 1024, "LDS overflow");

// ---------------- persistent scan kernel ----------------
struct ScanParams {
  const float* input;      // [512][64][384] fp32
  const unsigned* memt;    // mem_t [64][512][384] half, as uint
  const float* Wh[2];      // [192][192]
  const float* v[2];       // [192]
  const float* Wg[2];      // [768][768]
  const float* Wih[2];     // [768][576]
  const float* Whh[2];     // [192][576]
  const float* bih[2];     // [576]
  const float* bhh[2];     // [576]
  const unsigned* mp[2];   // mem_proj [512][64][192] half, as uint
  const __half* xp[2];     // x_proj [512][64][192] half (bw pre-reversed)
  float* h;                // [2 parity][2 dir][64][192]
  float* ctx;              // [2 dir][2 half][64][384] unnormalized partial
  float* Z;                // [2 dir][2 half][64]
  float* xcg;              // [2 dir][64][768]
  float* out;              // [512][64][384]
  unsigned* bar;
};

__global__ __launch_bounds__(512) void scan_kernel(ScanParams p) {
  extern __shared__ char smem[];
  __half* mp_s   = (__half*)(smem + L_MP);
  float* xcs     = (float*)(smem + L_OVL);   // [64][67]
  float* redp    = (float*)(smem + L_OVL);   // [8][384] (P1 only)
  float* wcs     = (float*)(smem + L_WCS);   // [64][8]
  float* gis     = (float*)(smem + L_GIS);   // [64][6]
  float* ghs     = (float*)(smem + L_GHS);   // [64][6]
  float* q_s     = (float*)(smem + L_Q);
  float* qp_s    = (float*)(smem + L_QP);
  float* h_s     = (float*)(smem + L_HS);
  float* v_s     = (float*)(smem + L_VS);
  float* invZ_s  = (float*)(smem + L_IZ);
  float* zp_s    = (float*)(smem + L_ZP);

  const int wg   = blockIdx.x;       // 0..255
  const int dir  = wg >> 7;
  const int j    = wg & 127;         // P2/P3 job index
  const int b    = j & 63;           // P1 batch
  const int half = j >> 6;           // P1 m-half
  const int tid  = threadIdx.x;
  const int lane = tid & 63;
  const int wv   = tid >> 6;

  const float* __restrict__ Wh  = p.Wh[dir];
  const float* __restrict__ Wg  = p.Wg[dir];
  const float* __restrict__ Wih = p.Wih[dir];
  const float* __restrict__ Whh = p.Whh[dir];
  const float* __restrict__ bih = p.bih[dir];
  const float* __restrict__ bhh = p.bhh[dir];
  const __half* __restrict__ xp = p.xp[dir];

  // ---- one-time: mem_proj half-slice -> LDS (t-invariant) ----
  {
    const unsigned* mpsrc = p.mp[dir];
    unsigned* mpd = (unsigned*)mp_s;
    const int m0 = half * 256;
    for (int idx = tid; idx < 256 * 96; idx += 512) {
      int r = idx / 96, a2 = idx - r * 96;
      mpd[idx] = mpsrc[((size_t)(m0 + r) * 64 + b) * 96 + a2];
    }
    if (tid < 192) v_s[tid] = p.v[dir][tid];
  }
  __syncthreads();
  const float v0 = v_s[lane], v1 = v_s[lane + 64], v2 = v_s[lane + 128];

  unsigned gen = 0;

  #pragma unroll 1
  for (int t = 0; t < TT; ++t) {
    const float* h_old = p.h + ((size_t)((t & 1) * 2 + dir) * 64) * 192;
    // =================== P1: attention for (dir, b, half) ===================
    if (tid < 192) h_s[tid] = h_old[b * 192 + tid];
    __syncthreads();
    if (tid < 384) {
      int hlf = (tid >= 192);
      int a = tid - hlf * 192;
      int j0 = hlf * 96;
      float acc = 0.f;
      #pragma unroll 4
      for (int jj = 0; jj < 96; ++jj) acc = fmaf(h_s[j0 + jj], Wh[(j0 + jj) * 192 + a], acc);
      qp_s[tid] = acc;
    }
    __syncthreads();
    if (tid < 192)
      q_s[tid] = __half2float(xp[((size_t)t * 64 + b) * 192 + tid]) + qp_s[tid] + qp_s[192 + tid];
    __syncthreads();

    {
      const float q0 = q_s[lane], q1 = q_s[lane + 64], q2 = q_s[lane + 128];
      float zacc = 0.f;
      float c0 = 0, c1 = 0, c2 = 0, c3 = 0, c4 = 0, c5 = 0;
      const int m0 = half * 256 + wv * 32;
      const unsigned* mrow = p.memt + ((size_t)b * MM + m0) * 192;
      const __half* mps = mp_s + (wv * 32) * 192;
      #pragma unroll 2
      for (int i = 0; i < 32; ++i) {
        const __half* row = mps + i * 192;
        float s = v0 * fast_tanh(__half2float(row[lane]) + q0)
                + v1 * fast_tanh(__half2float(row[lane + 64]) + q1)
                + v2 * fast_tanh(__half2float(row[lane + 128]) + q2);
        #pragma unroll
        for (int off = 32; off > 0; off >>= 1) s += __shfl_xor(s, off, 64);
        float e = __expf(s);
        zacc += e;
        const unsigned* mr = mrow + (size_t)i * 192;
        float2 f0 = h2f2(mr[lane]);
        float2 f1 = h2f2(mr[lane + 64]);
        float2 f2 = h2f2(mr[lane + 128]);
        c0 = fmaf(e, f0.x, c0); c1 = fmaf(e, f0.y, c1);
        c2 = fmaf(e, f1.x, c2); c3 = fmaf(e, f1.y, c3);
        c4 = fmaf(e, f2.x, c4); c5 = fmaf(e, f2.y, c5);
      }
      float* rp = redp + wv * 384;
      rp[2 * lane]       = c0; rp[2 * lane + 1]   = c1;
      rp[2 * lane + 128] = c2; rp[2 * lane + 129] = c3;
      rp[2 * lane + 256] = c4; rp[2 * lane + 257] = c5;
      if (lane == 0) zp_s[wv] = zacc;
    }
    __syncthreads();
    if (tid < 384) {
      float c = 0.f;
      #pragma unroll
      for (int k = 0; k < 8; ++k) c += redp[k * 384 + tid];
      p.ctx[(((size_t)dir * 2 + half) * 64 + b) * 384 + tid] = c;
    }
    if (tid == 0) {
      float z = 0.f;
      #pragma unroll
      for (int k = 0; k < 8; ++k) z += zp_s[k];
      p.Z[((size_t)dir * 2 + half) * 64 + b] = z;
    }
    gen++; grid_barrier(p.bar, gen * (unsigned)NWG);

    // =================== P2: xcg cols {j+128i} = sigmoid(xc@Wg)*xc ===================
    const int xt = dir ? (TT - 1 - t) : t;
    const float* xrow = p.input + (size_t)xt * 64 * 384;
    const float* ctx0 = p.ctx + ((size_t)dir * 2 + 0) * 64 * 384;
    const float* ctx1 = p.ctx + ((size_t)dir * 2 + 1) * 64 * 384;
    {
      if (tid < 64) {
        float z = p.Z[((size_t)dir * 2 + 0) * 64 + tid] + p.Z[((size_t)dir * 2 + 1) * 64 + tid];
        invZ_s[tid] = __builtin_amdgcn_rcpf(z);
      }
      __syncthreads();
      float acc[6] = {0, 0, 0, 0, 0, 0};
      for (int c = 0; c < 12; ++c) {
        int k0 = c * 64;
        if (k0 < 384) {
          for (int idx = tid; idx < 4096; idx += 512) {
            int bb = idx >> 6, kk = idx & 63;
            xcs[bb * 67 + kk] = xrow[bb * 384 + k0 + kk];
          }
        } else {
          int d0 = k0 - 384;
          for (int idx = tid; idx < 4096; idx += 512) {
            int bb = idx >> 6, kk = idx & 63;
            xcs[bb * 67 + kk] = (ctx0[bb * 384 + d0 + kk] + ctx1[bb * 384 + d0 + kk]) * invZ_s[bb];
          }
        }
        if (tid < 384) {
          int kk = tid / 6, cc = tid - kk * 6;
          wcs[kk * 8 + cc] = Wg[(size_t)(k0 + kk) * 768 + (j + 128 * cc)];
        }
        __syncthreads();
        #pragma unroll
        for (int i = 0; i < 8; ++i) {
          int kk = (wv << 3) + i;
          float xv = xcs[lane * 67 + kk];
          #pragma unroll
          for (int cc = 0; cc < 6; ++cc) acc[cc] = fmaf(xv, wcs[kk * 8 + cc], acc[cc]);
        }
        __syncthreads();
      }
      #pragma unroll
      for (int cc = 0; cc < 6; ++cc) xcs[((wv << 6) + lane) * 6 + cc] = acc[cc];
      __syncthreads();
      if (tid < 384) {
        int bb = tid / 6, cc = tid - bb * 6;
        float s = 0.f;
        #pragma unroll
        for (int ks = 0; ks < 8; ++ks) s += xcs[((ks << 6) + bb) * 6 + cc];
        int col = j + 128 * cc;
        float xv = (col < 384) ? xrow[bb * 384 + col]
                               : (ctx0[bb * 384 + col - 384] + ctx1[bb * 384 + col - 384]) * invZ_s[bb];
        p.xcg[((size_t)dir * 64 + bb) * 768 + col] = fast_sigmoid(s) * xv;
      }
    }
    gen++; grid_barrier(p.bar, gen * (unsigned)NWG);

    // =================== P3: gi/gh for hc {2j,2j+1}; GRU update ===================
    if (j < 96) {
      const int hc0 = 2 * j;
      int col6[6];
      #pragma unroll
      for (int cc = 0; cc < 6; ++cc) col6[cc] = (cc >> 1) * 192 + hc0 + (cc & 1);
      const float* xcgr = p.xcg + (size_t)dir * 64 * 768;
      float acc[6] = {0, 0, 0, 0, 0, 0};
      for (int c = 0; c < 12; ++c) {
        int k0 = c * 64;
        for (int idx = tid; idx < 4096; idx += 512) {
          int bb = idx >> 6, kk = idx & 63;
          xcs[bb * 67 + kk] = xcgr[bb * 768 + k0 + kk];
        }
        if (tid < 384) {
          int kk = tid / 6, cc = tid - kk * 6;
          wcs[kk * 8 + cc] = Wih[(size_t)(k0 + kk) * 576 + col6[cc]];
        }
        __syncthreads();
        #pragma unroll
        for (int i = 0; i < 8; ++i) {
          int kk = (wv << 3) + i;
          float xv = xcs[lane * 67 + kk];
          #pragma unroll
          for (int cc = 0; cc < 6; ++cc) acc[cc] = fmaf(xv, wcs[kk * 8 + cc], acc[cc]);
        }
        __syncthreads();
      }
      #pragma unroll
      for (int cc = 0; cc < 6; ++cc) xcs[((wv << 6) + lane) * 6 + cc] = acc[cc];
      __syncthreads();
      if (tid < 384) {
        int bb = tid / 6, cc = tid - bb * 6;
        float s = 0.f;
        #pragma unroll
        for (int ks = 0; ks < 8; ++ks) s += xcs[((ks << 6) + bb) * 6 + cc];
        gis[bb * 6 + cc] = s + bih[col6[cc]];
      }
      __syncthreads();
      // gh = h_old @ Whh + bhh (h_old stable: writes go to other parity buffer)
      float acc2[6] = {0, 0, 0, 0, 0, 0};
      for (int c = 0; c < 3; ++c) {
        int k0 = c * 64;
        for (int idx = tid; idx < 4096; idx += 512) {
          int bb = idx >> 6, kk = idx & 63;
          xcs[bb * 67 + kk] = h_old[bb * 192 + k0 + kk];
        }
        if (tid < 384) {
          int kk = tid / 6, cc = tid - kk * 6;
          wcs[kk * 8 + cc] = Whh[(size_t)(k0 + kk) * 576 + col6[cc]];
        }
        __syncthreads();
        #pragma unroll
        for (int i = 0; i < 8; ++i) {
          int kk = (wv << 3) + i;
          float xv = xcs[lane * 67 + kk];
          #pragma unroll
          for (int cc = 0; cc < 6; ++cc) acc2[cc] = fmaf(xv, wcs[kk * 8 + cc], acc2[cc]);
        }
        __syncthreads();
      }
      #pragma unroll
      for (int cc = 0; cc < 6; ++cc) xcs[((wv << 6) + lane) * 6 + cc] = acc2[cc];
      __syncthreads();
      if (tid < 384) {
        int bb = tid / 6, cc = tid - bb * 6;
        float s = 0.f;
        #pragma unroll
        for (int ks = 0; ks < 8; ++ks) s += xcs[((ks << 6) + bb) * 6 + cc];
        ghs[bb * 6 + cc] = s + bhh[col6[cc]];
      }
      __syncthreads();
      if (tid < 128) {
        int bb = tid & 63, c01 = tid >> 6;
        float r = fast_sigmoid(gis[bb * 6 + c01]     + ghs[bb * 6 + c01]);
        float z = fast_sigmoid(gis[bb * 6 + 2 + c01] + ghs[bb * 6 + 2 + c01]);
        float n = fast_tanh(gis[bb * 6 + 4 + c01] + r * ghs[bb * 6 + 4 + c01]);
        int hc = hc0 + c01;
        float hprev = h_old[bb * 192 + hc];
        float hnew = (1.f - z) * n + z * hprev;
        p.h[((size_t)(((t + 1) & 1) * 2 + dir) * 64 + bb) * 192 + hc] = hnew;
        int trow = dir ? (TT - 1 - t) : t;
        p.out[((size_t)trow * 64 + bb) * 384 + dir * 192 + hc] = hnew;
      }
    }
    gen++; grid_barrier(p.bar, gen * (unsigned)NWG);
  }
}

// ---------------- launcher ----------------
extern "C" void kernel_launch(void* const* d_in, const int* in_sizes, int n_in,
                              void* d_out, int out_size, void* d_ws, size_t ws_size,
                              hipStream_t stream) {
  (void)in_sizes; (void)n_in; (void)out_size;
  const float* memory = (const float*)d_in[0];
  const float* input  = (const float*)d_in[2];
  const float* Wm[2]  = {(const float*)d_in[3],  (const float*)d_in[12]};
  const float* Wx[2]  = {(const float*)d_in[4],  (const float*)d_in[13]};
  const float* Wh[2]  = {(const float*)d_in[5],  (const float*)d_in[14]};
  const float* v[2]   = {(const float*)d_in[6],  (const float*)d_in[15]};
  const float* Wg[2]  = {(const float*)d_in[7],  (const float*)d_in[16]};
  const float* Wih[2] = {(const float*)d_in[8],  (const float*)d_in[17]};
  const float* Whh[2] = {(const float*)d_in[9],  (const float*)d_in[18]};
  const float* bih[2] = {(const float*)d_in[10], (const float*)d_in[19]};
  const float* bhh[2] = {(const float*)d_in[11], (const float*)d_in[20]};

  // workspace layout (bytes)
  char* ws = (char*)d_ws;
  const size_t OFF_H   = 256;                         // 2*2*64*192*4 = 196608
  const size_t OFF_CTX = 196864;                      // 2*2*64*384*4 = 393216
  const size_t OFF_Z   = 590080;                      // 1024
  const size_t OFF_XCG = 591104;                      // 2*64*768*4 = 393216
  const size_t OFF_MP0 = 984320;                      // 512*64*192*2 = 12582912
  const size_t OFF_MP1 = OFF_MP0 + 12582912;
  const size_t OFF_XP0 = OFF_MP1 + 12582912;
  const size_t OFF_XP1 = OFF_XP0 + 12582912;
  const size_t OFF_MT  = OFF_XP1 + 12582912;          // 512*64*384*2 = 25165824
  const size_t NEEDED  = OFF_MT + 25165824;           // ~76.5 MB
  if (ws_size < NEEDED) return;

  unsigned* bar = (unsigned*)ws;
  float* h_buf  = (float*)(ws + OFF_H);
  float* ctx    = (float*)(ws + OFF_CTX);
  float* Zb     = (float*)(ws + OFF_Z);
  float* xcg    = (float*)(ws + OFF_XCG);
  __half* mp0   = (__half*)(ws + OFF_MP0);
  __half* mp1   = (__half*)(ws + OFF_MP1);
  __half* xp0   = (__half*)(ws + OFF_XP0);
  __half* xp1   = (__half*)(ws + OFF_XP1);
  __half* memt  = (__half*)(ws + OFF_MT);

  hipFuncSetAttribute(reinterpret_cast<const void*>(scan_kernel),
                      hipFuncAttributeMaxDynamicSharedMemorySize, SCAN_LDS);

  // zero barrier counter + both h parity buffers
  hipMemsetAsync(d_ws, 0, OFF_H + 196608, stream);

  ProjParams pp;
  pp.X[0] = memory; pp.W[0] = Wm[0]; pp.C[0] = mp0; pp.rev[0] = 0;
  pp.X[1] = memory; pp.W[1] = Wm[1]; pp.C[1] = mp1; pp.rev[1] = 0;
  pp.X[2] = input;  pp.W[2] = Wx[0]; pp.C[2] = xp0; pp.rev[2] = 0;
  pp.X[3] = input;  pp.W[3] = Wx[1]; pp.C[3] = xp1; pp.rev[3] = 1;
  proj_kernel<<<dim3(1024, 4), dim3(192), 0, stream>>>(pp);
  memcvt_kernel<<<dim3(MM, 64), dim3(384), 0, stream>>>(memory, memt);

  ScanParams sp;
  sp.input = input;
  sp.memt = (const unsigned*)memt;
  for (int d = 0; d < 2; ++d) {
    sp.Wh[d] = Wh[d]; sp.v[d] = v[d]; sp.Wg[d] = Wg[d];
    sp.Wih[d] = Wih[d]; sp.Whh[d] = Whh[d]; sp.bih[d] = bih[d]; sp.bhh[d] = bhh[d];
  }
  sp.mp[0] = (const unsigned*)mp0; sp.mp[1] = (const unsigned*)mp1;
  sp.xp[0] = xp0; sp.xp[1] = xp1;
  sp.h = h_buf; sp.ctx = ctx; sp.Z = Zb; sp.xcg = xcg;
  sp.out = (float*)d_out; sp.bar = bar;
  scan_kernel<<<dim3(NWG), dim3(512), SCAN_LDS, stream>>>(sp);
}

// Round 3
// 48749.786 us; speedup vs baseline: 3.6103x; 3.6103x over previous
//
#include <hip/hip_runtime.h>
#include <hip/hip_fp16.h>

#define TT 512
#define MM 512
#define NWG 256

// ---------------- fast math ----------------
__device__ __forceinline__ float fast_sigmoid(float x) {
  float e = __expf(-x);
  return __builtin_amdgcn_rcpf(1.f + e);
}
__device__ __forceinline__ float fast_tanh(float x) {
  float e = __expf(2.f * x);
  return 1.f - 2.f * __builtin_amdgcn_rcpf(e + 1.f);
}
__device__ __forceinline__ float2 h2f2(unsigned u) {
  __half2 h = *reinterpret_cast<__half2*>(&u);
  return __half22float2(h);
}
__device__ __forceinline__ unsigned pack2(float x, float y) {
  __half2 h = __floats2half2_rn(x, y);
  return *reinterpret_cast<unsigned*>(&h);
}

typedef _Float16 hf2_t __attribute__((ext_vector_type(2)));
__device__ __forceinline__ float fdot2f(unsigned a, unsigned b, float c) {
#if __has_builtin(__builtin_amdgcn_fdot2)
  union U { unsigned u; hf2_t h; };
  U ua, ub; ua.u = a; ub.u = b;
  return __builtin_amdgcn_fdot2(ua.h, ub.h, c, false);
#else
  float2 fa = h2f2(a), fb = h2f2(b);
  return fmaf(fa.x, fb.x, fmaf(fa.y, fb.y, c));
#endif
}

// ---------------- agent-scope atomics (coherence-point, no cache fences) ----------------
__device__ __forceinline__ void ast(float* p, float v) {
  __hip_atomic_store(p, v, __ATOMIC_RELAXED, __HIP_MEMORY_SCOPE_AGENT);
}
__device__ __forceinline__ float ald(const float* p) {
  return __hip_atomic_load(p, __ATOMIC_RELAXED, __HIP_MEMORY_SCOPE_AGENT);
}
__device__ __forceinline__ void astu(unsigned* p, unsigned v) {
  __hip_atomic_store(p, v, __ATOMIC_RELAXED, __HIP_MEMORY_SCOPE_AGENT);
}
__device__ __forceinline__ unsigned aldu(const unsigned* p) {
  return __hip_atomic_load(p, __ATOMIC_RELAXED, __HIP_MEMORY_SCOPE_AGENT);
}

// ---------------- precompute: proj (fp16 out, optional transpose / reversal) ----------------
struct ProjParams {
  const float* X[4]; const float* W[4]; __half* C[4]; int rev[4]; int transp[4];
};

__global__ __launch_bounds__(192) void proj_kernel(ProjParams pp) {
  __shared__ float xs[32 * 384];
  const int job = blockIdx.y;
  const float* __restrict__ X = pp.X[job];
  const float* __restrict__ W = pp.W[job];
  __half* __restrict__ C = pp.C[job];
  const int rev = pp.rev[job];
  const int transp = pp.transp[job];
  const int r0 = blockIdx.x * 32;
  const int tid = threadIdx.x;

  for (int idx = tid; idx < 32 * 384; idx += 192) {
    int r = idx / 384, k = idx - r * 384;
    int row = r0 + r;
    int srow = row;
    if (rev) { int t = row >> 6, b2 = row & 63; srow = ((TT - 1 - t) << 6) | b2; }
    xs[idx] = X[(size_t)srow * 384 + k];
  }
  __syncthreads();

  float acc[32];
  #pragma unroll
  for (int r = 0; r < 32; ++r) acc[r] = 0.f;
  for (int k = 0; k < 384; ++k) {
    float w = W[k * 192 + tid];
    #pragma unroll
    for (int r = 0; r < 32; ++r) acc[r] = fmaf(xs[r * 384 + k], w, acc[r]);
  }
  #pragma unroll
  for (int r = 0; r < 32; ++r) {
    int row = r0 + r;
    size_t di = transp ? (((size_t)(row & 63) * MM + (row >> 6)) * 192 + tid)
                       : ((size_t)row * 192 + tid);
    C[di] = __float2half(acc[r]);
  }
}

// memt[b][m][d] = half(memory[m][b][d])
__global__ __launch_bounds__(384) void memcvt_kernel(const float* __restrict__ src,
                                                     __half* __restrict__ dst) {
  int m = blockIdx.x, b = blockIdx.y, d = threadIdx.x;
  dst[((size_t)b * MM + m) * 384 + d] = __float2half(src[((size_t)m * 64 + b) * 384 + d]);
}

// k-pair interleaved fp16 weights: dst[k2*N+j] = pack(src[2k2][j], src[2k2+1][j])
struct WcvtParams { const float* src[8]; unsigned* dst[8]; int tot[8]; int N[8]; };
__global__ __launch_bounds__(256) void wcvt_kernel(WcvtParams wp) {
  int job = blockIdx.y;
  const float* __restrict__ s = wp.src[job];
  unsigned* __restrict__ d = wp.dst[job];
  int n = wp.N[job], tot = wp.tot[job];
  for (int i = blockIdx.x * 256 + threadIdx.x; i < tot; i += gridDim.x * 256) {
    int k2 = i / n, j = i - k2 * n;
    d[i] = pack2(s[(size_t)(2 * k2) * n + j], s[(size_t)(2 * k2 + 1) * n + j]);
  }
}

// ---------------- LDS layout (bytes) ----------------
#define L_MP     0        // 256*192 halfs = 98304
#define L_REDP   98304    // 8*384 f = 12288
#define L_SH384  110592   // qpart / ctx_mine overlay: 384 f = 1536
#define L_Q      112128   // 192 f
#define L_XCF    112896   // 768 f = 3072
#define L_XC2    115968   // 384 u = 1536
#define L_G2     117504   // 384 u = 1536
#define L_GIS    119040   // 576 f = 2304
#define L_GHS    121344   // 576 f = 2304
#define L_HF     123648   // 192 f = 768
#define L_H2     124416   // 96 u = 384
#define L_VS     124800   // 192 f = 768
#define L_ZP     125568   // 8 f = 32
#define L_MISC   125600   // 8 f = 32
#define SCAN_LDS 125632
static_assert(SCAN_LDS <= 160 * 1024, "LDS overflow");

struct ScanParams {
  const float* input;        // [512][64][384] f32
  const unsigned* memt;      // [64][512][192] u (384 halfs)
  const unsigned* mpt[2];    // [64][512][96] u (192 halfs)
  const __half* xp[2];       // [512][64][192] half
  const unsigned* Wh2[2];    // [96][192] u
  const unsigned* Wg2[2];    // [384][768] u
  const unsigned* Wih2[2];   // [384][576] u
  const unsigned* Whh2[2];   // [96][576] u
  const float* v[2];
  const float* bih[2];
  const float* bhh[2];
  float* exch_ctx;           // [2 dir][2 half][64 b][2 par][384]
  float* exch_z;             // [2][2][64][2]
  unsigned* flags;           // [2][2][64]
  float* out;                // [512][64][384]
};

__global__ __launch_bounds__(512, 1) void scan_kernel(ScanParams p) {
  extern __shared__ char smem[];
  __half*   mp_s   = (__half*)(smem + L_MP);
  float*    redp   = (float*)(smem + L_REDP);
  float*    sh384  = (float*)(smem + L_SH384);   // qpart then ctx_mine
  float*    q_s    = (float*)(smem + L_Q);
  float*    xc_f   = (float*)(smem + L_XCF);
  unsigned* xc2_s  = (unsigned*)(smem + L_XC2);
  unsigned* g2_s   = (unsigned*)(smem + L_G2);
  float*    gis    = (float*)(smem + L_GIS);
  float*    ghs    = (float*)(smem + L_GHS);
  float*    h_f    = (float*)(smem + L_HF);
  unsigned* h2_s   = (unsigned*)(smem + L_H2);
  float*    v_s    = (float*)(smem + L_VS);
  float*    zp_s   = (float*)(smem + L_ZP);
  float*    misc_s = (float*)(smem + L_MISC);

  // XCD-grouped mapping: xcd 0-3 -> dir0, 4-7 -> dir1 (weights L2-resident per XCD)
  const int g = blockIdx.x;
  const int xcd = g & 7;
  const int slot = g >> 3;
  const int dir = xcd >> 2;
  const int idx = (xcd & 3) * 32 + slot;   // 0..127
  const int b = idx & 63;
  const int half = idx >> 6;
  const int tid = threadIdx.x;
  const int lane = tid & 63;
  const int wv = tid >> 6;

  const unsigned* __restrict__ Wh2  = p.Wh2[dir];
  const unsigned* __restrict__ Wg2  = p.Wg2[dir];
  const unsigned* __restrict__ Wih2 = p.Wih2[dir];
  const unsigned* __restrict__ Whh2 = p.Whh2[dir];
  const float* __restrict__ bih = p.bih[dir];
  const float* __restrict__ bhh = p.bhh[dir];
  const __half* __restrict__ xp = p.xp[dir];
  const int m0 = half * 256;

  // exchange slots
  float* myctx0 = p.exch_ctx + (((size_t)(dir * 2 + half) * 64 + b) * 2) * 384;
  float* pctx0  = p.exch_ctx + (((size_t)(dir * 2 + (half ^ 1)) * 64 + b) * 2) * 384;
  float* myz0   = p.exch_z + ((size_t)(dir * 2 + half) * 64 + b) * 2;
  float* pz0    = p.exch_z + ((size_t)(dir * 2 + (half ^ 1)) * 64 + b) * 2;
  unsigned* myflag = p.flags + (size_t)(dir * 2 + half) * 64 + b;
  unsigned* pflag  = p.flags + (size_t)(dir * 2 + (half ^ 1)) * 64 + b;

  // ---- init: mp half-slice -> LDS; h = 0; v -> LDS ----
  {
    const unsigned* mpu = p.mpt[dir] + ((size_t)b * MM + m0) * 96;
    unsigned* mpd = (unsigned*)mp_s;
    for (int i = tid; i < 256 * 96; i += 512) mpd[i] = mpu[i];
    if (tid < 192) { h_f[tid] = 0.f; v_s[tid] = p.v[dir][tid]; }
    if (tid < 96) h2_s[tid] = 0u;
  }
  __syncthreads();
  const float v0 = v_s[lane], v1 = v_s[lane + 64], v2 = v_s[lane + 128];

  #pragma unroll 1
  for (int t = 0; t < TT; ++t) {
    const int par = t & 1;
    // ---- q = xp[t,b,:] + h @ Wh ----
    if (tid < 384) {
      const int kh = (tid >= 192);
      const int a = tid - kh * 192;
      const unsigned* wr = Wh2 + kh * 48 * 192;
      float acc = 0.f;
      #pragma unroll 4
      for (int i = 0; i < 48; ++i)
        acc = fdot2f(wr[i * 192 + a], h2_s[kh * 48 + i], acc);
      sh384[kh * 192 + a] = acc;
    }
    __syncthreads();
    if (tid < 192)
      q_s[tid] = __half2float(xp[((size_t)t * 64 + b) * 192 + tid]) + sh384[tid] + sh384[192 + tid];
    __syncthreads();

    // ---- scores + context over my 256-row half ----
    {
      const float q0 = q_s[lane], q1 = q_s[lane + 64], q2 = q_s[lane + 128];
      float zacc = 0.f;
      float c0 = 0, c1 = 0, c2 = 0, c3 = 0, c4 = 0, c5 = 0;
      const unsigned* mrow = p.memt + ((size_t)b * MM + m0 + wv * 32) * 192;
      const __half* mph = mp_s + (wv * 32) * 192;
      #pragma unroll 2
      for (int i = 0; i < 32; ++i) {
        const __half* r = mph + i * 192;
        float s = v0 * fast_tanh(__half2float(r[lane]) + q0)
                + v1 * fast_tanh(__half2float(r[lane + 64]) + q1)
                + v2 * fast_tanh(__half2float(r[lane + 128]) + q2);
        #pragma unroll
        for (int off = 32; off > 0; off >>= 1) s += __shfl_xor(s, off, 64);
        float e = __expf(s);
        zacc += e;
        const unsigned* mr = mrow + (size_t)i * 192;
        float2 f0 = h2f2(mr[lane]);
        float2 f1 = h2f2(mr[lane + 64]);
        float2 f2 = h2f2(mr[lane + 128]);
        c0 = fmaf(e, f0.x, c0); c1 = fmaf(e, f0.y, c1);
        c2 = fmaf(e, f1.x, c2); c3 = fmaf(e, f1.y, c3);
        c4 = fmaf(e, f2.x, c4); c5 = fmaf(e, f2.y, c5);
      }
      float* rp = redp + wv * 384;
      rp[2 * lane]       = c0; rp[2 * lane + 1]   = c1;
      rp[2 * lane + 128] = c2; rp[2 * lane + 129] = c3;
      rp[2 * lane + 256] = c4; rp[2 * lane + 257] = c5;
      if (lane == 0) zp_s[wv] = zacc;
    }
    __syncthreads();

    // ---- combine partials; send my half (agent atomics, no fences) ----
    float cm = 0.f, zs = 0.f;
    if (tid < 384) {
      #pragma unroll
      for (int k = 0; k < 8; ++k) cm += redp[k * 384 + tid];
      sh384[tid] = cm;
      ast(myctx0 + par * 384 + tid, cm);
    }
    if (tid == 0) {
      #pragma unroll
      for (int k = 0; k < 8; ++k) zs += zp_s[k];
      ast(myz0 + par, zs);
    }
    __syncthreads();   // drains all stores (vmcnt 0 before barrier)

    // ---- flag handshake + partner read; overlap x-load ----
    if (tid == 0) {
      astu(myflag, (unsigned)(t + 1));
      while (aldu(pflag) < (unsigned)(t + 1)) __builtin_amdgcn_s_sleep(1);
      float pz = ald(pz0 + par);
      misc_s[0] = __builtin_amdgcn_rcpf(zs + pz);
    }
    const int xt = dir ? (TT - 1 - t) : t;
    if (tid < 384) xc_f[tid] = p.input[((size_t)xt * 64 + b) * 384 + tid];
    __syncthreads();
    if (tid < 384) {
      float pc = ald(pctx0 + par * 384 + tid);
      xc_f[384 + tid] = (sh384[tid] + pc) * misc_s[0];
    }
    __syncthreads();
    if (tid < 384) xc2_s[tid] = pack2(xc_f[2 * tid], xc_f[2 * tid + 1]);
    __syncthreads();

    // ---- gate: g = sigmoid(xc @ Wg) * xc ----
    if (tid < 384) {
      float a0 = 0.f, a1 = 0.f;
      const uint2* wr = (const uint2*)Wg2;
      #pragma unroll 4
      for (int k2 = 0; k2 < 384; ++k2) {
        uint2 w = wr[(size_t)k2 * 384 + tid];
        unsigned x2 = xc2_s[k2];
        a0 = fdot2f(w.x, x2, a0);
        a1 = fdot2f(w.y, x2, a1);
      }
      float g0 = fast_sigmoid(a0) * xc_f[2 * tid];
      float g1 = fast_sigmoid(a1) * xc_f[2 * tid + 1];
      g2_s[tid] = pack2(g0, g1);
    }
    __syncthreads();

    // ---- gi = g @ Wih + bih ; gh = h @ Whh + bhh ----
    if (tid < 288) {
      float a0 = 0.f, a1 = 0.f;
      const uint2* wr = (const uint2*)Wih2;
      #pragma unroll 4
      for (int k2 = 0; k2 < 384; ++k2) {
        uint2 w = wr[(size_t)k2 * 288 + tid];
        unsigned x2 = g2_s[k2];
        a0 = fdot2f(w.x, x2, a0);
        a1 = fdot2f(w.y, x2, a1);
      }
      gis[2 * tid]     = a0 + bih[2 * tid];
      gis[2 * tid + 1] = a1 + bih[2 * tid + 1];
    } else {
      int j = tid - 288;
      #pragma unroll 1
      for (int rep = 0; rep < 2; ++rep, j += 224) {
        if (j < 288) {
          float a0 = 0.f, a1 = 0.f;
          const uint2* wr = (const uint2*)Whh2;
          #pragma unroll 4
          for (int k2 = 0; k2 < 96; ++k2) {
            uint2 w = wr[(size_t)k2 * 288 + j];
            unsigned hh = h2_s[k2];
            a0 = fdot2f(w.x, hh, a0);
            a1 = fdot2f(w.y, hh, a1);
          }
          ghs[2 * j]     = a0 + bhh[2 * j];
          ghs[2 * j + 1] = a1 + bhh[2 * j + 1];
        }
      }
    }
    __syncthreads();

    // ---- GRU update (identical in both pair-WGs) ----
    if (tid < 192) {
      float r = fast_sigmoid(gis[tid] + ghs[tid]);
      float z = fast_sigmoid(gis[192 + tid] + ghs[192 + tid]);
      float n = fast_tanh(gis[384 + tid] + r * ghs[384 + tid]);
      float hnew = (1.f - z) * n + z * h_f[tid];
      h_f[tid] = hnew;
      if (half == 0) {
        int trow = dir ? (TT - 1 - t) : t;
        p.out[((size_t)trow * 64 + b) * 384 + dir * 192 + tid] = hnew;
      }
    }
    __syncthreads();
    if (tid < 96) h2_s[tid] = pack2(h_f[2 * tid], h_f[2 * tid + 1]);
    __syncthreads();
  }
}

// ---------------- launcher ----------------
extern "C" void kernel_launch(void* const* d_in, const int* in_sizes, int n_in,
                              void* d_out, int out_size, void* d_ws, size_t ws_size,
                              hipStream_t stream) {
  (void)in_sizes; (void)n_in; (void)out_size;
  const float* memory = (const float*)d_in[0];
  const float* input  = (const float*)d_in[2];
  const float* Wm[2]  = {(const float*)d_in[3],  (const float*)d_in[12]};
  const float* Wx[2]  = {(const float*)d_in[4],  (const float*)d_in[13]};
  const float* Wh[2]  = {(const float*)d_in[5],  (const float*)d_in[14]};
  const float* v[2]   = {(const float*)d_in[6],  (const float*)d_in[15]};
  const float* Wg[2]  = {(const float*)d_in[7],  (const float*)d_in[16]};
  const float* Wih[2] = {(const float*)d_in[8],  (const float*)d_in[17]};
  const float* Whh[2] = {(const float*)d_in[9],  (const float*)d_in[18]};
  const float* bih[2] = {(const float*)d_in[10], (const float*)d_in[19]};
  const float* bhh[2] = {(const float*)d_in[11], (const float*)d_in[20]};

  char* ws = (char*)d_ws;
  const size_t OFF_FLAGS = 0;            // 1024
  const size_t OFF_EZ    = 1024;         // 2048
  const size_t OFF_ECTX  = 4096;         // 1,572,864
  const size_t OFF_MPT0  = OFF_ECTX + 1572864;
  const size_t OFF_MPT1  = OFF_MPT0 + 12582912;
  const size_t OFF_XP0   = OFF_MPT1 + 12582912;
  const size_t OFF_XP1   = OFF_XP0 + 12582912;
  const size_t OFF_MT    = OFF_XP1 + 12582912;
  const size_t OFF_WG0   = OFF_MT + 25165824;
  const size_t OFF_WG1   = OFF_WG0 + 1179648;
  const size_t OFF_WIH0  = OFF_WG1 + 1179648;
  const size_t OFF_WIH1  = OFF_WIH0 + 884736;
  const size_t OFF_WHH0  = OFF_WIH1 + 884736;
  const size_t OFF_WHH1  = OFF_WHH0 + 221184;
  const size_t OFF_WH0   = OFF_WHH1 + 221184;
  const size_t OFF_WH1   = OFF_WH0 + 73728;
  const size_t NEEDED    = OFF_WH1 + 73728;   // ~94.4 MB
  if (ws_size < NEEDED) return;

  unsigned* flags = (unsigned*)(ws + OFF_FLAGS);
  float* ez    = (float*)(ws + OFF_EZ);
  float* ectx  = (float*)(ws + OFF_ECTX);
  __half* mpt0 = (__half*)(ws + OFF_MPT0);
  __half* mpt1 = (__half*)(ws + OFF_MPT1);
  __half* xp0  = (__half*)(ws + OFF_XP0);
  __half* xp1  = (__half*)(ws + OFF_XP1);
  __half* memt = (__half*)(ws + OFF_MT);
  unsigned* wg2[2]  = {(unsigned*)(ws + OFF_WG0),  (unsigned*)(ws + OFF_WG1)};
  unsigned* wih2[2] = {(unsigned*)(ws + OFF_WIH0), (unsigned*)(ws + OFF_WIH1)};
  unsigned* whh2[2] = {(unsigned*)(ws + OFF_WHH0), (unsigned*)(ws + OFF_WHH1)};
  unsigned* wh2[2]  = {(unsigned*)(ws + OFF_WH0),  (unsigned*)(ws + OFF_WH1)};

  hipFuncSetAttribute(reinterpret_cast<const void*>(scan_kernel),
                      hipFuncAttributeMaxDynamicSharedMemorySize, SCAN_LDS);

  hipMemsetAsync(ws + OFF_FLAGS, 0, 1024, stream);   // flags only

  ProjParams pp;
  pp.X[0] = memory; pp.W[0] = Wm[0]; pp.C[0] = mpt0; pp.rev[0] = 0; pp.transp[0] = 1;
  pp.X[1] = memory; pp.W[1] = Wm[1]; pp.C[1] = mpt1; pp.rev[1] = 0; pp.transp[1] = 1;
  pp.X[2] = input;  pp.W[2] = Wx[0]; pp.C[2] = xp0;  pp.rev[2] = 0; pp.transp[2] = 0;
  pp.X[3] = input;  pp.W[3] = Wx[1]; pp.C[3] = xp1;  pp.rev[3] = 1; pp.transp[3] = 0;
  proj_kernel<<<dim3(1024, 4), dim3(192), 0, stream>>>(pp);
  memcvt_kernel<<<dim3(MM, 64), dim3(384), 0, stream>>>(memory, memt);

  WcvtParams wp;
  for (int d = 0; d < 2; ++d) {
    wp.src[d]     = Wg[d];  wp.dst[d]     = wg2[d];  wp.tot[d]     = 384 * 768; wp.N[d]     = 768;
    wp.src[2 + d] = Wih[d]; wp.dst[2 + d] = wih2[d]; wp.tot[2 + d] = 384 * 576; wp.N[2 + d] = 576;
    wp.src[4 + d] = Whh[d]; wp.dst[4 + d] = whh2[d]; wp.tot[4 + d] = 96 * 576;  wp.N[4 + d] = 576;
    wp.src[6 + d] = Wh[d];  wp.dst[6 + d] = wh2[d];  wp.tot[6 + d] = 96 * 192;  wp.N[6 + d] = 192;
  }
  wcvt_kernel<<<dim3(288, 8), dim3(256), 0, stream>>>(wp);

  ScanParams sp;
  sp.input = input;
  sp.memt = (const unsigned*)memt;
  sp.mpt[0] = (const unsigned*)mpt0; sp.mpt[1] = (const unsigned*)mpt1;
  sp.xp[0] = xp0; sp.xp[1] = xp1;
  for (int d = 0; d < 2; ++d) {
    sp.Wh2[d] = wh2[d]; sp.Wg2[d] = wg2[d]; sp.Wih2[d] = wih2[d]; sp.Whh2[d] = whh2[d];
    sp.v[d] = v[d]; sp.bih[d] = bih[d]; sp.bhh[d] = bhh[d];
  }
  sp.exch_ctx = ectx; sp.exch_z = ez; sp.flags = flags;
  sp.out = (float*)d_out;
  scan_kernel<<<dim3(NWG), dim3(512), SCAN_LDS, stream>>>(sp);
}

// Round 4
// 23453.865 us; speedup vs baseline: 7.5042x; 2.0785x over previous
//
#include <hip/hip_runtime.h>
#include <hip/hip_fp16.h>

#define TT 512
#define MM 512
#define NWG 256

// ---------------- fast math ----------------
__device__ __forceinline__ float fast_sigmoid(float x) {
  float e = __expf(-x);
  return __builtin_amdgcn_rcpf(1.f + e);
}
__device__ __forceinline__ float fast_tanh(float x) {
  float e = __expf(2.f * x);
  return 1.f - 2.f * __builtin_amdgcn_rcpf(e + 1.f);
}
__device__ __forceinline__ float2 h2f2(unsigned u) {
  __half2 h = *reinterpret_cast<__half2*>(&u);
  return __half22float2(h);
}
__device__ __forceinline__ unsigned pack2(float x, float y) {
  __half2 h = __floats2half2_rn(x, y);
  return *reinterpret_cast<unsigned*>(&h);
}

typedef _Float16 hf2_t __attribute__((ext_vector_type(2)));
__device__ __forceinline__ float fdot2f(unsigned a, unsigned b, float c) {
#if __has_builtin(__builtin_amdgcn_fdot2)
  union U { unsigned u; hf2_t h; };
  U ua, ub; ua.u = a; ub.u = b;
  return __builtin_amdgcn_fdot2(ua.h, ub.h, c, false);
#else
  float2 fa = h2f2(a), fb = h2f2(b);
  return fmaf(fa.x, fb.x, fmaf(fa.y, fb.y, c));
#endif
}

// 16-deep software-pipelined dot: w strided by S (global), x2 in LDS. K%16==0.
template<int K, int S>
__device__ __forceinline__ float dotpipe(const unsigned* __restrict__ w,
                                         const unsigned* __restrict__ x2) {
  unsigned A[8], B[8];
  float a0 = 0.f, a1 = 0.f, a2 = 0.f, a3 = 0.f;
  #pragma unroll
  for (int i = 0; i < 8; ++i) A[i] = w[(size_t)i * S];
  #pragma unroll 1
  for (int k = 0; k < K; k += 16) {
    #pragma unroll
    for (int i = 0; i < 8; ++i) B[i] = w[(size_t)(k + 8 + i) * S];
    #pragma unroll
    for (int i = 0; i < 8; ++i) {
      if ((i & 3) == 0)      a0 = fdot2f(A[i], x2[k + i], a0);
      else if ((i & 3) == 1) a1 = fdot2f(A[i], x2[k + i], a1);
      else if ((i & 3) == 2) a2 = fdot2f(A[i], x2[k + i], a2);
      else                   a3 = fdot2f(A[i], x2[k + i], a3);
    }
    if (k + 16 < K) {
      #pragma unroll
      for (int i = 0; i < 8; ++i) A[i] = w[(size_t)(k + 16 + i) * S];
    }
    #pragma unroll
    for (int i = 0; i < 8; ++i) {
      if ((i & 3) == 0)      a0 = fdot2f(B[i], x2[k + 8 + i], a0);
      else if ((i & 3) == 1) a1 = fdot2f(B[i], x2[k + 8 + i], a1);
      else if ((i & 3) == 2) a2 = fdot2f(B[i], x2[k + 8 + i], a2);
      else                   a3 = fdot2f(B[i], x2[k + 8 + i], a3);
    }
  }
  return (a0 + a1) + (a2 + a3);
}

// ---------------- agent-scope atomics (coherence-point, no cache fences) ----------------
__device__ __forceinline__ void ast(float* p, float v) {
  __hip_atomic_store(p, v, __ATOMIC_RELAXED, __HIP_MEMORY_SCOPE_AGENT);
}
__device__ __forceinline__ float ald(const float* p) {
  return __hip_atomic_load(p, __ATOMIC_RELAXED, __HIP_MEMORY_SCOPE_AGENT);
}
__device__ __forceinline__ void astu(unsigned* p, unsigned v) {
  __hip_atomic_store(p, v, __ATOMIC_RELAXED, __HIP_MEMORY_SCOPE_AGENT);
}
__device__ __forceinline__ unsigned aldu(const unsigned* p) {
  return __hip_atomic_load(p, __ATOMIC_RELAXED, __HIP_MEMORY_SCOPE_AGENT);
}
__device__ __forceinline__ void astull(unsigned long long* p, unsigned long long v) {
  __hip_atomic_store(p, v, __ATOMIC_RELAXED, __HIP_MEMORY_SCOPE_AGENT);
}
__device__ __forceinline__ unsigned long long aldull(const unsigned long long* p) {
  return __hip_atomic_load(p, __ATOMIC_RELAXED, __HIP_MEMORY_SCOPE_AGENT);
}
union F2U { unsigned long long u; float f[2]; };

// ---------------- precompute: proj (fp16 out, optional transpose / reversal) ----------------
struct ProjParams {
  const float* X[4]; const float* W[4]; __half* C[4]; int rev[4]; int transp[4];
};

__global__ __launch_bounds__(192) void proj_kernel(ProjParams pp) {
  __shared__ float xs[32 * 384];
  const int job = blockIdx.y;
  const float* __restrict__ X = pp.X[job];
  const float* __restrict__ W = pp.W[job];
  __half* __restrict__ C = pp.C[job];
  const int rev = pp.rev[job];
  const int transp = pp.transp[job];
  const int r0 = blockIdx.x * 32;
  const int tid = threadIdx.x;

  for (int idx = tid; idx < 32 * 384; idx += 192) {
    int r = idx / 384, k = idx - r * 384;
    int row = r0 + r;
    int srow = row;
    if (rev) { int t = row >> 6, b2 = row & 63; srow = ((TT - 1 - t) << 6) | b2; }
    xs[idx] = X[(size_t)srow * 384 + k];
  }
  __syncthreads();

  float acc[32];
  #pragma unroll
  for (int r = 0; r < 32; ++r) acc[r] = 0.f;
  for (int k = 0; k < 384; ++k) {
    float w = W[k * 192 + tid];
    #pragma unroll
    for (int r = 0; r < 32; ++r) acc[r] = fmaf(xs[r * 384 + k], w, acc[r]);
  }
  #pragma unroll
  for (int r = 0; r < 32; ++r) {
    int row = r0 + r;
    size_t di = transp ? (((size_t)(row & 63) * MM + (row >> 6)) * 192 + tid)
                       : ((size_t)row * 192 + tid);
    C[di] = __float2half(acc[r]);
  }
}

// memt[b][m][d] = half(memory[m][b][d])
__global__ __launch_bounds__(384) void memcvt_kernel(const float* __restrict__ src,
                                                     __half* __restrict__ dst) {
  int m = blockIdx.x, b = blockIdx.y, d = threadIdx.x;
  dst[((size_t)b * MM + m) * 384 + d] = __float2half(src[((size_t)m * 64 + b) * 384 + d]);
}

// k-pair interleaved fp16 weights: dst[k2*N+j] = pack(src[2k2][j], src[2k2+1][j])
struct WcvtParams { const float* src[8]; unsigned* dst[8]; int tot[8]; int N[8]; };
__global__ __launch_bounds__(256) void wcvt_kernel(WcvtParams wp) {
  int job = blockIdx.y;
  const float* __restrict__ s = wp.src[job];
  unsigned* __restrict__ d = wp.dst[job];
  int n = wp.N[job], tot = wp.tot[job];
  for (int i = blockIdx.x * 256 + threadIdx.x; i < tot; i += gridDim.x * 256) {
    int k2 = i / n, j = i - k2 * n;
    d[i] = pack2(s[(size_t)(2 * k2) * n + j], s[(size_t)(2 * k2 + 1) * n + j]);
  }
}

// ---------------- LDS layout (bytes) ----------------
#define L_MP     0         // 256*192 halfs = 98304
#define L_REDP   98304     // 8*384 f = 12288
#define L_SH384  110592    // q-parts / ctx sums / raw g overlay: 384 f
#define L_Q      112128    // 192 f
#define L_XCF    112896    // 768 f
#define L_XC2    115968    // 384 u
#define L_G2     117504    // 384 u
#define L_GIS    119040    // 288 f
#define L_GHS    120192    // 288 f
#define L_HF     121344    // 192 f
#define L_H2     122112    // 96 u
#define L_VS     122496    // 192 f
#define L_BIH    123264    // 288 f
#define L_BHH    124416    // 288 f
#define L_ZP     125568    // 8 f
#define L_MISC   125600    // 8 f
#define SCAN_LDS 125632
static_assert(SCAN_LDS <= 160 * 1024, "LDS overflow");

struct ScanParams {
  const float* input;        // [512][64][384] f32
  const unsigned* memt;      // [64][512][192] u (384 halfs)
  const unsigned* mpt[2];    // [64][512][96] u (192 halfs)
  const __half* xp[2];       // [512][64][192] half
  const unsigned* Wh2[2];    // [96][192] u
  const unsigned* Wg2[2];    // [384][768] u
  const unsigned* Wih2[2];   // [384][576] u
  const unsigned* Whh2[2];   // [96][576] u
  const float* v[2];
  const float* bih[2];
  const float* bhh[2];
  unsigned long long* ectx;  // [dirhalf][b][2 par][192] f32-pairs
  float* ez;                 // [dirhalf][b][2 par]
  unsigned* gmail;           // [dirhalf][b][2 par][192] packed half2
  unsigned* hmail;           // [dirhalf][b][2 par][48] packed half2
  unsigned* flags;           // 3 arrays x [dirhalf][b]
  float* out;                // [512][64][384]
};

__global__ __launch_bounds__(512, 1) void scan_kernel(ScanParams p) {
  extern __shared__ char smem[];
  __half*   mp_s   = (__half*)(smem + L_MP);
  float*    redp   = (float*)(smem + L_REDP);
  float*    sh384  = (float*)(smem + L_SH384);
  float*    q_s    = (float*)(smem + L_Q);
  float*    xc_f   = (float*)(smem + L_XCF);
  unsigned* xc2_s  = (unsigned*)(smem + L_XC2);
  unsigned* g2_s   = (unsigned*)(smem + L_G2);
  float*    gis    = (float*)(smem + L_GIS);
  float*    ghs    = (float*)(smem + L_GHS);
  float*    h_f    = (float*)(smem + L_HF);
  unsigned* h2_s   = (unsigned*)(smem + L_H2);
  float*    v_s    = (float*)(smem + L_VS);
  float*    bih_s  = (float*)(smem + L_BIH);
  float*    bhh_s  = (float*)(smem + L_BHH);
  float*    zp_s   = (float*)(smem + L_ZP);
  float*    misc_s = (float*)(smem + L_MISC);

  // XCD-grouped mapping: xcd 0-3 -> dir0, 4-7 -> dir1
  const int g = blockIdx.x;
  const int xcd = g & 7;
  const int slot = g >> 3;
  const int dir = xcd >> 2;
  const int idx = (xcd & 3) * 32 + slot;   // 0..127
  const int b = idx & 63;
  const int half = idx >> 6;
  const int tid = threadIdx.x;
  const int lane = tid & 63;
  const int wv = tid >> 6;

  const unsigned* __restrict__ Wh2  = p.Wh2[dir];
  const unsigned* __restrict__ Wg2  = p.Wg2[dir];
  const unsigned* __restrict__ Wih2 = p.Wih2[dir];
  const unsigned* __restrict__ Whh2 = p.Whh2[dir];
  const __half* __restrict__ xp = p.xp[dir];
  const int m0 = half * 256;

  const int idx_my = (dir * 2 + half) * 64 + b;
  const int idx_p  = (dir * 2 + (half ^ 1)) * 64 + b;
  unsigned long long* myctx_u = p.ectx + (size_t)idx_my * 2 * 192;
  const unsigned long long* pctx_u = p.ectx + (size_t)idx_p * 2 * 192;
  float* myz0 = p.ez + (size_t)idx_my * 2;
  const float* pz0 = p.ez + (size_t)idx_p * 2;
  unsigned* gmail_my = p.gmail + (size_t)idx_my * 2 * 192;
  const unsigned* gmail_p = p.gmail + (size_t)idx_p * 2 * 192;
  unsigned* hmail_my = p.hmail + (size_t)idx_my * 2 * 48;
  const unsigned* hmail_p = p.hmail + (size_t)idx_p * 2 * 48;
  unsigned* fctx_my = p.flags + idx_my;        const unsigned* fctx_p = p.flags + idx_p;
  unsigned* fg_my   = p.flags + 256 + idx_my;  const unsigned* fg_p   = p.flags + 256 + idx_p;
  unsigned* fh_my   = p.flags + 512 + idx_my;  const unsigned* fh_p   = p.flags + 512 + idx_p;

  // ---- init ----
  {
    const unsigned* mpu = p.mpt[dir] + ((size_t)b * MM + m0) * 96;
    unsigned* mpd = (unsigned*)mp_s;
    for (int i = tid; i < 256 * 96; i += 512) mpd[i] = mpu[i];
    if (tid < 192) { h_f[tid] = 0.f; v_s[tid] = p.v[dir][tid]; }
    if (tid < 96) h2_s[tid] = 0u;
    if (tid < 288) {
      int c3 = tid / 96, jj = tid - c3 * 96;
      int col = c3 * 192 + 96 * half + jj;
      bih_s[tid] = p.bih[dir][col];
      bhh_s[tid] = p.bhh[dir][col];
    }
  }
  __syncthreads();
  const float v0 = v_s[lane], v1 = v_s[lane + 64], v2 = v_s[lane + 128];

  #pragma unroll 1
  for (int t = 0; t < TT; ++t) {
    const int par = t & 1;
    // ---- A: q = xp[t,b,:] + h @ Wh ----
    if (tid < 384) {
      const int kh = (tid >= 192);
      const int a = tid - 192 * kh;
      sh384[tid] = dotpipe<48, 192>(Wh2 + (size_t)kh * 48 * 192 + a, h2_s + kh * 48);
    }
    __syncthreads();
    if (tid < 192)
      q_s[tid] = __half2float(xp[((size_t)t * 64 + b) * 192 + tid]) + sh384[tid] + sh384[192 + tid];
    __syncthreads();

    // ---- B: scores + context over my 256-row half (prefetched memt) ----
    {
      const float q0 = q_s[lane], q1 = q_s[lane + 64], q2 = q_s[lane + 128];
      float zacc = 0.f;
      float c0 = 0, c1 = 0, c2 = 0, c3 = 0, c4 = 0, c5 = 0;
      const unsigned* mrow = p.memt + ((size_t)b * MM + m0 + wv * 32) * 192;
      const __half* mph = mp_s + (wv * 32) * 192;
      unsigned m0r = mrow[lane], m1r = mrow[lane + 64], m2r = mrow[lane + 128];
      #pragma unroll 1
      for (int i = 0; i < 32; ++i) {
        const unsigned* nr = mrow + (size_t)((i + 1) & 31) * 192;
        unsigned n0 = nr[lane], n1 = nr[lane + 64], n2 = nr[lane + 128];
        const __half* r = mph + i * 192;
        float s = v0 * fast_tanh(__half2float(r[lane]) + q0)
                + v1 * fast_tanh(__half2float(r[lane + 64]) + q1)
                + v2 * fast_tanh(__half2float(r[lane + 128]) + q2);
        #pragma unroll
        for (int off = 32; off > 0; off >>= 1) s += __shfl_xor(s, off, 64);
        float e = __expf(s);
        zacc += e;
        float2 f0 = h2f2(m0r), f1 = h2f2(m1r), f2 = h2f2(m2r);
        c0 = fmaf(e, f0.x, c0); c1 = fmaf(e, f0.y, c1);
        c2 = fmaf(e, f1.x, c2); c3 = fmaf(e, f1.y, c3);
        c4 = fmaf(e, f2.x, c4); c5 = fmaf(e, f2.y, c5);
        m0r = n0; m1r = n1; m2r = n2;
      }
      float* rp = redp + wv * 384;
      rp[2 * lane]       = c0; rp[2 * lane + 1]   = c1;
      rp[2 * lane + 128] = c2; rp[2 * lane + 129] = c3;
      rp[2 * lane + 256] = c4; rp[2 * lane + 257] = c5;
      if (lane == 0) zp_s[wv] = zacc;
    }
    __syncthreads();

    // ---- C: combine partials, send (f32 pairs via 64-bit atomics); overlap x-load ----
    float zs = 0.f;
    if (tid < 192) {
      float cm0 = 0.f, cm1 = 0.f;
      #pragma unroll
      for (int k = 0; k < 8; ++k) { cm0 += redp[k * 384 + 2 * tid]; cm1 += redp[k * 384 + 2 * tid + 1]; }
      sh384[2 * tid] = cm0; sh384[2 * tid + 1] = cm1;
      F2U u; u.f[0] = cm0; u.f[1] = cm1;
      astull(myctx_u + par * 192 + tid, u.u);
    }
    if (tid == 0) {
      #pragma unroll
      for (int k = 0; k < 8; ++k) zs += zp_s[k];
      ast(myz0 + par, zs);
    }
    const int xt = dir ? (TT - 1 - t) : t;
    if (tid < 384) xc_f[tid] = p.input[((size_t)xt * 64 + b) * 384 + tid];
    __syncthreads();   // drains atomic stores (vmcnt 0 before barrier)
    if (tid == 0) {
      astu(fctx_my, (unsigned)(t + 1));
      while (aldu(fctx_p) < (unsigned)(t + 1)) __builtin_amdgcn_s_sleep(1);
      float pz = ald(pz0 + par);
      misc_s[0] = __builtin_amdgcn_rcpf(zs + pz);
    }
    __syncthreads();

    // ---- D: xc build ----
    if (tid < 192) {
      F2U u; u.u = aldull(pctx_u + par * 192 + tid);
      float iz = misc_s[0];
      xc_f[384 + 2 * tid]     = (sh384[2 * tid] + u.f[0]) * iz;
      xc_f[384 + 2 * tid + 1] = (sh384[2 * tid + 1] + u.f[1]) * iz;
    }
    __syncthreads();
    if (tid < 384) xc2_s[tid] = pack2(xc_f[2 * tid], xc_f[2 * tid + 1]);
    __syncthreads();

    // ---- E: gate (my 384 cols) ----
    if (tid < 384) {
      const int col = 384 * half + tid;
      float acc = dotpipe<384, 768>(Wg2 + col, xc2_s);
      sh384[tid] = fast_sigmoid(acc) * xc_f[col];
    }
    __syncthreads();
    if (tid < 192) {
      unsigned pk = pack2(sh384[2 * tid], sh384[2 * tid + 1]);
      g2_s[192 * half + tid] = pk;
      astu(gmail_my + par * 192 + tid, pk);
    }
    __syncthreads();   // drain mailbox stores
    if (tid == 0) astu(fg_my, (unsigned)(t + 1));
    // overlap partner's gate tail with my gh = h @ Whh + bhh
    if (tid < 288) {
      const int c3 = tid / 96, jj = tid - c3 * 96;
      const int col = c3 * 192 + 96 * half + jj;
      ghs[tid] = dotpipe<96, 576>(Whh2 + col, h2_s) + bhh_s[tid];
    }
    __syncthreads();
    if (tid == 0) {
      while (aldu(fg_p) < (unsigned)(t + 1)) __builtin_amdgcn_s_sleep(1);
    }
    __syncthreads();
    // ---- F: fetch partner g half ----
    if (tid < 192) g2_s[192 * (1 - half) + tid] = aldu(gmail_p + par * 192 + tid);
    __syncthreads();

    // ---- G: gi (my 288 cols) ----
    if (tid < 288) {
      const int c3 = tid / 96, jj = tid - c3 * 96;
      const int col = c3 * 192 + 96 * half + jj;
      gis[tid] = dotpipe<384, 576>(Wih2 + col, g2_s) + bih_s[tid];
    }
    __syncthreads();

    // ---- H: GRU update (my 96 j's) ----
    if (tid < 96) {
      const int j = 96 * half + tid;
      float r = fast_sigmoid(gis[tid] + ghs[tid]);
      float z = fast_sigmoid(gis[96 + tid] + ghs[96 + tid]);
      float n = fast_tanh(gis[192 + tid] + r * ghs[192 + tid]);
      float hnew = (1.f - z) * n + z * h_f[j];
      h_f[j] = hnew;
      int trow = dir ? (TT - 1 - t) : t;
      p.out[((size_t)trow * 64 + b) * 384 + dir * 192 + j] = hnew;
    }
    __syncthreads();
    if (tid < 48) {
      unsigned pk = pack2(h_f[96 * half + 2 * tid], h_f[96 * half + 2 * tid + 1]);
      h2_s[48 * half + tid] = pk;
      astu(hmail_my + par * 48 + tid, pk);
    }
    __syncthreads();   // drain
    if (tid == 0) {
      astu(fh_my, (unsigned)(t + 1));
      while (aldu(fh_p) < (unsigned)(t + 1)) __builtin_amdgcn_s_sleep(1);
    }
    __syncthreads();
    if (tid < 48) h2_s[48 * (1 - half) + tid] = aldu(hmail_p + par * 48 + tid);
    __syncthreads();
  }
}

// ---------------- launcher ----------------
extern "C" void kernel_launch(void* const* d_in, const int* in_sizes, int n_in,
                              void* d_out, int out_size, void* d_ws, size_t ws_size,
                              hipStream_t stream) {
  (void)in_sizes; (void)n_in; (void)out_size;
  const float* memory = (const float*)d_in[0];
  const float* input  = (const float*)d_in[2];
  const float* Wm[2]  = {(const float*)d_in[3],  (const float*)d_in[12]};
  const float* Wx[2]  = {(const float*)d_in[4],  (const float*)d_in[13]};
  const float* Wh[2]  = {(const float*)d_in[5],  (const float*)d_in[14]};
  const float* v[2]   = {(const float*)d_in[6],  (const float*)d_in[15]};
  const float* Wg[2]  = {(const float*)d_in[7],  (const float*)d_in[16]};
  const float* Wih[2] = {(const float*)d_in[8],  (const float*)d_in[17]};
  const float* Whh[2] = {(const float*)d_in[9],  (const float*)d_in[18]};
  const float* bih[2] = {(const float*)d_in[10], (const float*)d_in[19]};
  const float* bhh[2] = {(const float*)d_in[11], (const float*)d_in[20]};

  char* ws = (char*)d_ws;
  const size_t OFF_FLAGS = 0;         // 4096 (3 flag arrays x 256 u32)
  const size_t OFF_EZ    = 4096;      // 2048
  const size_t OFF_GMAIL = 6144;      // 786432
  const size_t OFF_HMAIL = 792576;    // 196608
  const size_t OFF_ECTX  = 989184;    // 786432
  const size_t OFF_MPT0  = 1775616;
  const size_t OFF_MPT1  = OFF_MPT0 + 12582912;
  const size_t OFF_XP0   = OFF_MPT1 + 12582912;
  const size_t OFF_XP1   = OFF_XP0 + 12582912;
  const size_t OFF_MT    = OFF_XP1 + 12582912;
  const size_t OFF_WG0   = OFF_MT + 25165824;
  const size_t OFF_WG1   = OFF_WG0 + 1179648;
  const size_t OFF_WIH0  = OFF_WG1 + 1179648;
  const size_t OFF_WIH1  = OFF_WIH0 + 884736;
  const size_t OFF_WHH0  = OFF_WIH1 + 884736;
  const size_t OFF_WHH1  = OFF_WHH0 + 221184;
  const size_t OFF_WH0   = OFF_WHH1 + 221184;
  const size_t OFF_WH1   = OFF_WH0 + 73728;
  const size_t NEEDED    = OFF_WH1 + 73728;   // ~82 MB
  if (ws_size < NEEDED) return;

  unsigned* flags = (unsigned*)(ws + OFF_FLAGS);
  float* ez    = (float*)(ws + OFF_EZ);
  unsigned* gmail = (unsigned*)(ws + OFF_GMAIL);
  unsigned* hmail = (unsigned*)(ws + OFF_HMAIL);
  unsigned long long* ectx = (unsigned long long*)(ws + OFF_ECTX);
  __half* mpt0 = (__half*)(ws + OFF_MPT0);
  __half* mpt1 = (__half*)(ws + OFF_MPT1);
  __half* xp0  = (__half*)(ws + OFF_XP0);
  __half* xp1  = (__half*)(ws + OFF_XP1);
  __half* memt = (__half*)(ws + OFF_MT);
  unsigned* wg2[2]  = {(unsigned*)(ws + OFF_WG0),  (unsigned*)(ws + OFF_WG1)};
  unsigned* wih2[2] = {(unsigned*)(ws + OFF_WIH0), (unsigned*)(ws + OFF_WIH1)};
  unsigned* whh2[2] = {(unsigned*)(ws + OFF_WHH0), (unsigned*)(ws + OFF_WHH1)};
  unsigned* wh2[2]  = {(unsigned*)(ws + OFF_WH0),  (unsigned*)(ws + OFF_WH1)};

  hipFuncSetAttribute(reinterpret_cast<const void*>(scan_kernel),
                      hipFuncAttributeMaxDynamicSharedMemorySize, SCAN_LDS);

  hipMemsetAsync(ws + OFF_FLAGS, 0, 4096, stream);   // flags only

  ProjParams pp;
  pp.X[0] = memory; pp.W[0] = Wm[0]; pp.C[0] = mpt0; pp.rev[0] = 0; pp.transp[0] = 1;
  pp.X[1] = memory; pp.W[1] = Wm[1]; pp.C[1] = mpt1; pp.rev[1] = 0; pp.transp[1] = 1;
  pp.X[2] = input;  pp.W[2] = Wx[0]; pp.C[2] = xp0;  pp.rev[2] = 0; pp.transp[2] = 0;
  pp.X[3] = input;  pp.W[3] = Wx[1]; pp.C[3] = xp1;  pp.rev[3] = 1; pp.transp[3] = 0;
  proj_kernel<<<dim3(1024, 4), dim3(192), 0, stream>>>(pp);
  memcvt_kernel<<<dim3(MM, 64), dim3(384), 0, stream>>>(memory, memt);

  WcvtParams wp;
  for (int d = 0; d < 2; ++d) {
    wp.src[d]     = Wg[d];  wp.dst[d]     = wg2[d];  wp.tot[d]     = 384 * 768; wp.N[d]     = 768;
    wp.src[2 + d] = Wih[d]; wp.dst[2 + d] = wih2[d]; wp.tot[2 + d] = 384 * 576; wp.N[2 + d] = 576;
    wp.src[4 + d] = Whh[d]; wp.dst[4 + d] = whh2[d]; wp.tot[4 + d] = 96 * 576;  wp.N[4 + d] = 576;
    wp.src[6 + d] = Wh[d];  wp.dst[6 + d] = wh2[d];  wp.tot[6 + d] = 96 * 192;  wp.N[6 + d] = 192;
  }
  wcvt_kernel<<<dim3(288, 8), dim3(256), 0, stream>>>(wp);

  ScanParams sp;
  sp.input = input;
  sp.memt = (const unsigned*)memt;
  sp.mpt[0] = (const unsigned*)mpt0; sp.mpt[1] = (const unsigned*)mpt1;
  sp.xp[0] = xp0; sp.xp[1] = xp1;
  for (int d = 0; d < 2; ++d) {
    sp.Wh2[d] = wh2[d]; sp.Wg2[d] = wg2[d]; sp.Wih2[d] = wih2[d]; sp.Whh2[d] = whh2[d];
    sp.v[d] = v[d]; sp.bih[d] = bih[d]; sp.bhh[d] = bhh[d];
  }
  sp.ectx = ectx; sp.ez = ez; sp.gmail = gmail; sp.hmail = hmail; sp.flags = flags;
  sp.out = (float*)d_out;
  scan_kernel<<<dim3(NWG), dim3(512), SCAN_LDS, stream>>>(sp);
}

// Round 5
// 22180.688 us; speedup vs baseline: 7.9349x; 1.0574x over previous
//
#include <hip/hip_runtime.h>
#include <hip/hip_fp16.h>

#define TT 512
#define MM 512
#define NWG 256

// ---------------- fast math ----------------
__device__ __forceinline__ float fast_sigmoid(float x) {
  float e = __expf(-x);
  return __builtin_amdgcn_rcpf(1.f + e);
}
__device__ __forceinline__ float fast_tanh(float x) {
  float e = __expf(2.f * x);
  return 1.f - 2.f * __builtin_amdgcn_rcpf(e + 1.f);
}
__device__ __forceinline__ float2 h2f2(unsigned u) {
  __half2 h = *reinterpret_cast<__half2*>(&u);
  return __half22float2(h);
}
__device__ __forceinline__ unsigned pack2(float x, float y) {
  __half2 h = __floats2half2_rn(x, y);
  return *reinterpret_cast<unsigned*>(&h);
}

typedef _Float16 hf2_t __attribute__((ext_vector_type(2)));
__device__ __forceinline__ float fdot2f(unsigned a, unsigned b, float c) {
#if __has_builtin(__builtin_amdgcn_fdot2)
  union U { unsigned u; hf2_t h; };
  U ua, ub; ua.u = a; ub.u = b;
  return __builtin_amdgcn_fdot2(ua.h, ub.h, c, false);
#else
  float2 fa = h2f2(a), fb = h2f2(b);
  return fmaf(fa.x, fb.x, fmaf(fa.y, fb.y, c));
#endif
}

// 24-deep software-pipelined dot: w strided by S (global), x2 in LDS. K%24==0.
template<int K, int S>
__device__ __forceinline__ float dotpipe(const unsigned* __restrict__ w,
                                         const unsigned* __restrict__ x2) {
  unsigned A[12], B[12];
  float acc[4] = {0.f, 0.f, 0.f, 0.f};
  #pragma unroll
  for (int i = 0; i < 12; ++i) A[i] = w[(size_t)i * S];
  #pragma unroll 1
  for (int k = 0; k < K; k += 24) {
    #pragma unroll
    for (int i = 0; i < 12; ++i) B[i] = w[(size_t)(k + 12 + i) * S];
    #pragma unroll
    for (int i = 0; i < 12; ++i) acc[i & 3] = fdot2f(A[i], x2[k + i], acc[i & 3]);
    if (k + 24 < K) {
      #pragma unroll
      for (int i = 0; i < 12; ++i) A[i] = w[(size_t)(k + 24 + i) * S];
    }
    #pragma unroll
    for (int i = 0; i < 12; ++i) acc[i & 3] = fdot2f(B[i], x2[k + 12 + i], acc[i & 3]);
  }
  return (acc[0] + acc[1]) + (acc[2] + acc[3]);
}

// ---------------- agent-scope atomics (coherence-point, no cache fences) ----------------
__device__ __forceinline__ void ast(float* p, float v) {
  __hip_atomic_store(p, v, __ATOMIC_RELAXED, __HIP_MEMORY_SCOPE_AGENT);
}
__device__ __forceinline__ float ald(const float* p) {
  return __hip_atomic_load(p, __ATOMIC_RELAXED, __HIP_MEMORY_SCOPE_AGENT);
}
__device__ __forceinline__ void astu(unsigned* p, unsigned v) {
  __hip_atomic_store(p, v, __ATOMIC_RELAXED, __HIP_MEMORY_SCOPE_AGENT);
}
__device__ __forceinline__ unsigned aldu(const unsigned* p) {
  return __hip_atomic_load(p, __ATOMIC_RELAXED, __HIP_MEMORY_SCOPE_AGENT);
}
__device__ __forceinline__ void astull(unsigned long long* p, unsigned long long v) {
  __hip_atomic_store(p, v, __ATOMIC_RELAXED, __HIP_MEMORY_SCOPE_AGENT);
}
__device__ __forceinline__ unsigned long long aldull(const unsigned long long* p) {
  return __hip_atomic_load(p, __ATOMIC_RELAXED, __HIP_MEMORY_SCOPE_AGENT);
}
union F2U { unsigned long long u; float f[2]; };

// ---------------- precompute: proj (fp16 out, optional transpose / reversal) ----------------
struct ProjParams {
  const float* X[4]; const float* W[4]; __half* C[4]; int rev[4]; int transp[4];
};

__global__ __launch_bounds__(192) void proj_kernel(ProjParams pp) {
  __shared__ float xs[32 * 384];
  const int job = blockIdx.y;
  const float* __restrict__ X = pp.X[job];
  const float* __restrict__ W = pp.W[job];
  __half* __restrict__ C = pp.C[job];
  const int rev = pp.rev[job];
  const int transp = pp.transp[job];
  const int r0 = blockIdx.x * 32;
  const int tid = threadIdx.x;

  for (int idx = tid; idx < 32 * 384; idx += 192) {
    int r = idx / 384, k = idx - r * 384;
    int row = r0 + r;
    int srow = row;
    if (rev) { int t = row >> 6, b2 = row & 63; srow = ((TT - 1 - t) << 6) | b2; }
    xs[idx] = X[(size_t)srow * 384 + k];
  }
  __syncthreads();

  float acc[32];
  #pragma unroll
  for (int r = 0; r < 32; ++r) acc[r] = 0.f;
  for (int k = 0; k < 384; ++k) {
    float w = W[k * 192 + tid];
    #pragma unroll
    for (int r = 0; r < 32; ++r) acc[r] = fmaf(xs[r * 384 + k], w, acc[r]);
  }
  #pragma unroll
  for (int r = 0; r < 32; ++r) {
    int row = r0 + r;
    size_t di = transp ? (((size_t)(row & 63) * MM + (row >> 6)) * 192 + tid)
                       : ((size_t)row * 192 + tid);
    C[di] = __float2half(acc[r]);
  }
}

// memt[b][m][d] = half(memory[m][b][d])
__global__ __launch_bounds__(384) void memcvt_kernel(const float* __restrict__ src,
                                                     __half* __restrict__ dst) {
  int m = blockIdx.x, b = blockIdx.y, d = threadIdx.x;
  dst[((size_t)b * MM + m) * 384 + d] = __float2half(src[((size_t)m * 64 + b) * 384 + d]);
}

// k-pair interleaved fp16 weights: dst[k2*N+j] = pack(src[2k2][j], src[2k2+1][j])
struct WcvtParams { const float* src[8]; unsigned* dst[8]; int tot[8]; int N[8]; };
__global__ __launch_bounds__(256) void wcvt_kernel(WcvtParams wp) {
  int job = blockIdx.y;
  const float* __restrict__ s = wp.src[job];
  unsigned* __restrict__ d = wp.dst[job];
  int n = wp.N[job], tot = wp.tot[job];
  for (int i = blockIdx.x * 256 + threadIdx.x; i < tot; i += gridDim.x * 256) {
    int k2 = i / n, j = i - k2 * n;
    d[i] = pack2(s[(size_t)(2 * k2) * n + j], s[(size_t)(2 * k2 + 1) * n + j]);
  }
}

// ---------------- LDS layout (bytes) ----------------
#define L_MP     0         // 256*192 halfs = 98304
#define L_REDP   98304     // 8*384 f = 12288
#define L_SH384  110592    // q-parts / ctx-mine / raw g overlay: 384 f
#define L_Q      112128    // 192 f
#define L_XCF    112896    // 768 f
#define L_XC2    115968    // 384 u
#define L_G2     117504    // 384 u
#define L_GIS    119040    // 288 f
#define L_GHS    120192    // 288 f
#define L_HF     121344    // 192 f
#define L_H2     122112    // 96 u
#define L_VS     122496    // 192 f
#define L_BIH    123264    // 288 f
#define L_BHH    124416    // 288 f
#define L_ZP     125568    // 8 f
#define L_MISC   125600    // 8 f
#define L_ES     125632    // 256 f = 1024
#define SCAN_LDS 126656
static_assert(SCAN_LDS <= 160 * 1024, "LDS overflow");

struct ScanParams {
  const float* input;        // [512][64][384] f32
  const unsigned* memt;      // [64][512][192] u (384 halfs)
  const unsigned* mpt[2];    // [64][512][96] u (192 halfs)
  const __half* xp[2];       // [512][64][192] half
  const unsigned* Wh2[2];    // [96][192] u
  const unsigned* Wg2[2];    // [384][768] u
  const unsigned* Wih2[2];   // [384][576] u
  const unsigned* Whh2[2];   // [96][576] u
  const float* v[2];
  const float* bih[2];
  const float* bhh[2];
  unsigned long long* ectx;  // [dirhalf][b][2 par][192] f32-pairs
  float* ez;                 // [dirhalf][b][2 par]
  unsigned* gmail;           // [dirhalf][b][2 par][192] packed half2
  unsigned* hmail;           // [dirhalf][b][2 par][48] packed half2
  unsigned* flags;           // 3 arrays x [dirhalf][b]
  float* out;                // [512][64][384]
};

__global__ __launch_bounds__(512, 1) void scan_kernel(ScanParams p) {
  extern __shared__ char smem[];
  __half*   mp_s   = (__half*)(smem + L_MP);
  float*    redp   = (float*)(smem + L_REDP);
  float*    sh384  = (float*)(smem + L_SH384);
  float*    q_s    = (float*)(smem + L_Q);
  float*    xc_f   = (float*)(smem + L_XCF);
  unsigned* xc2_s  = (unsigned*)(smem + L_XC2);
  unsigned* g2_s   = (unsigned*)(smem + L_G2);
  float*    gis    = (float*)(smem + L_GIS);
  float*    ghs    = (float*)(smem + L_GHS);
  float*    h_f    = (float*)(smem + L_HF);
  unsigned* h2_s   = (unsigned*)(smem + L_H2);
  float*    v_s    = (float*)(smem + L_VS);
  float*    bih_s  = (float*)(smem + L_BIH);
  float*    bhh_s  = (float*)(smem + L_BHH);
  float*    zp_s   = (float*)(smem + L_ZP);
  float*    misc_s = (float*)(smem + L_MISC);
  float*    e_s    = (float*)(smem + L_ES);

  // XCD-grouped mapping: xcd 0-3 -> dir0, 4-7 -> dir1
  const int g = blockIdx.x;
  const int xcd = g & 7;
  const int slot = g >> 3;
  const int dir = xcd >> 2;
  const int idx = (xcd & 3) * 32 + slot;   // 0..127
  const int b = idx & 63;
  const int half = idx >> 6;
  const int tid = threadIdx.x;
  const int lane = tid & 63;
  const int wv = tid >> 6;

  const unsigned* __restrict__ Wh2  = p.Wh2[dir];
  const unsigned* __restrict__ Wg2  = p.Wg2[dir];
  const unsigned* __restrict__ Wih2 = p.Wih2[dir];
  const unsigned* __restrict__ Whh2 = p.Whh2[dir];
  const __half* __restrict__ xp = p.xp[dir];
  const int m0 = half * 256;

  const int idx_my = (dir * 2 + half) * 64 + b;
  const int idx_p  = (dir * 2 + (half ^ 1)) * 64 + b;
  unsigned long long* myctx_u = p.ectx + (size_t)idx_my * 2 * 192;
  const unsigned long long* pctx_u = p.ectx + (size_t)idx_p * 2 * 192;
  float* myz0 = p.ez + (size_t)idx_my * 2;
  const float* pz0 = p.ez + (size_t)idx_p * 2;
  unsigned* gmail_my = p.gmail + (size_t)idx_my * 2 * 192;
  const unsigned* gmail_p = p.gmail + (size_t)idx_p * 2 * 192;
  unsigned* hmail_my = p.hmail + (size_t)idx_my * 2 * 48;
  const unsigned* hmail_p = p.hmail + (size_t)idx_p * 2 * 48;
  unsigned* fctx_my = p.flags + idx_my;        const unsigned* fctx_p = p.flags + idx_p;
  unsigned* fg_my   = p.flags + 256 + idx_my;  const unsigned* fg_p   = p.flags + 256 + idx_p;
  unsigned* fh_my   = p.flags + 512 + idx_my;  const unsigned* fh_p   = p.flags + 512 + idx_p;

  // ---- init ----
  {
    const unsigned* mpu = p.mpt[dir] + ((size_t)b * MM + m0) * 96;
    unsigned* mpd = (unsigned*)mp_s;
    for (int i = tid; i < 256 * 96; i += 512) mpd[i] = mpu[i];
    if (tid < 192) { h_f[tid] = 0.f; v_s[tid] = p.v[dir][tid]; }
    if (tid < 96) h2_s[tid] = 0u;
    if (tid < 288) {
      int c3 = tid / 96, jj = tid - c3 * 96;
      int col = c3 * 192 + 96 * half + jj;
      bih_s[tid] = p.bih[dir][col];
      bhh_s[tid] = p.bhh[dir][col];
    }
  }
  __syncthreads();
  const float v0 = v_s[lane], v1 = v_s[lane + 64], v2 = v_s[lane + 128];

  #pragma unroll 1
  for (int t = 0; t < TT; ++t) {
    const int par = t & 1;
    // ---- A: q = xp[t,b,:] + h @ Wh ----
    if (tid < 384) {
      const int kh = (tid >= 192);
      const int a = tid - 192 * kh;
      sh384[tid] = dotpipe<48, 192>(Wh2 + (size_t)kh * 48 * 192 + a, h2_s + kh * 48);
    }
    __syncthreads();
    if (tid < 192)
      q_s[tid] = __half2float(xp[((size_t)t * 64 + b) * 192 + tid]) + sh384[tid] + sh384[192 + tid];
    __syncthreads();

    // ---- B1: scores for my 256 rows -> e_s, per-wave Z ----
    {
      const float q0 = q_s[lane], q1 = q_s[lane + 64], q2 = q_s[lane + 128];
      float zacc = 0.f;
      const __half* mph = mp_s + (wv * 32) * 192;
      #pragma unroll 4
      for (int i = 0; i < 32; ++i) {
        const __half* r = mph + i * 192;
        float s = v0 * fast_tanh(__half2float(r[lane]) + q0)
                + v1 * fast_tanh(__half2float(r[lane + 64]) + q1)
                + v2 * fast_tanh(__half2float(r[lane + 128]) + q2);
        #pragma unroll
        for (int off = 32; off > 0; off >>= 1) s += __shfl_xor(s, off, 64);
        float e = __expf(s);
        zacc += e;
        if (lane == 0) e_s[wv * 32 + i] = e;
      }
      if (lane == 0) zp_s[wv] = zacc;
    }
    // ---- B2: context c[6*lane..6*lane+5] += e[m]*memt[m] (pipelined, uint3) ----
    {
      float c0 = 0, c1 = 0, c2 = 0, c3 = 0, c4 = 0, c5 = 0;
      const uint3* mrow3 = (const uint3*)(p.memt + ((size_t)b * MM + m0 + wv * 32) * 192);
      const float* es = e_s + wv * 32;
      #pragma unroll 8
      for (int i = 0; i < 32; ++i) {
        uint3 mv = mrow3[(size_t)i * 64 + lane];
        float e = es[i];
        float2 f0 = h2f2(mv.x), f1 = h2f2(mv.y), f2 = h2f2(mv.z);
        c0 = fmaf(e, f0.x, c0); c1 = fmaf(e, f0.y, c1);
        c2 = fmaf(e, f1.x, c2); c3 = fmaf(e, f1.y, c3);
        c4 = fmaf(e, f2.x, c4); c5 = fmaf(e, f2.y, c5);
      }
      float2* rp2 = (float2*)(redp + wv * 384);
      rp2[3 * lane]     = make_float2(c0, c1);
      rp2[3 * lane + 1] = make_float2(c2, c3);
      rp2[3 * lane + 2] = make_float2(c4, c5);
    }
    __syncthreads();

    // ---- C: combine partials, send; load input row ----
    float zs = 0.f;
    if (tid < 192) {
      float cm0 = 0.f, cm1 = 0.f;
      const float2* rp2 = (const float2*)redp;
      #pragma unroll
      for (int k = 0; k < 8; ++k) {
        float2 v2r = rp2[k * 192 + tid];
        cm0 += v2r.x; cm1 += v2r.y;
      }
      sh384[2 * tid] = cm0; sh384[2 * tid + 1] = cm1;
      F2U u; u.f[0] = cm0; u.f[1] = cm1;
      astull(myctx_u + par * 192 + tid, u.u);
    }
    if (tid == 0) {
      #pragma unroll
      for (int k = 0; k < 8; ++k) zs += zp_s[k];
      ast(myz0 + par, zs);
    }
    const int xt = dir ? (TT - 1 - t) : t;
    if (tid < 384) xc_f[tid] = p.input[((size_t)xt * 64 + b) * 384 + tid];
    __syncthreads();   // drains atomic stores; xc_f ready
    if (tid < 192) xc2_s[tid] = pack2(xc_f[2 * tid], xc_f[2 * tid + 1]);
    if (tid == 0) astu(fctx_my, (unsigned)(t + 1));
    __syncthreads();   // xc2 input half visible

    // ---- E1: gate partial over input half (overlaps partner ctx wait) ----
    float eacc = 0.f;
    if (tid < 384) {
      const int col = 384 * half + tid;
      eacc = dotpipe<192, 768>(Wg2 + col, xc2_s);
    }
    // ---- ghs on idle waves 6-7 (needs only h2_s, stable this step) ----
    if (tid >= 384) {
      for (int jj = tid - 384; jj < 288; jj += 128) {
        const int c3 = jj / 96;
        const int col = c3 * 192 + 96 * half + (jj - c3 * 96);
        ghs[jj] = dotpipe<96, 576>(Whh2 + col, h2_s) + bhh_s[jj];
      }
    }
    if (tid == 0) {
      while (aldu(fctx_p) < (unsigned)(t + 1)) __builtin_amdgcn_s_sleep(1);
      float pz = ald(pz0 + par);
      misc_s[0] = __builtin_amdgcn_rcpf(zs + pz);
    }
    __syncthreads();

    // ---- D: ctx half of xc ----
    if (tid < 192) {
      F2U u; u.u = aldull(pctx_u + par * 192 + tid);
      float iz = misc_s[0];
      float x0 = (sh384[2 * tid] + u.f[0]) * iz;
      float x1 = (sh384[2 * tid + 1] + u.f[1]) * iz;
      xc_f[384 + 2 * tid] = x0;
      xc_f[384 + 2 * tid + 1] = x1;
      xc2_s[192 + tid] = pack2(x0, x1);
    }
    __syncthreads();

    // ---- E2: finish gate ----
    if (tid < 384) {
      const int col = 384 * half + tid;
      eacc += dotpipe<192, 768>(Wg2 + (size_t)192 * 768 + col, xc2_s + 192);
      sh384[tid] = fast_sigmoid(eacc) * xc_f[col];
    }
    __syncthreads();
    if (tid < 192) {
      unsigned pk = pack2(sh384[2 * tid], sh384[2 * tid + 1]);
      g2_s[192 * half + tid] = pk;
      astu(gmail_my + par * 192 + tid, pk);
    }
    __syncthreads();   // drain mailbox stores
    if (tid == 0) astu(fg_my, (unsigned)(t + 1));

    // ---- G1: gi partial over my g half (overlaps partner gate) ----
    float gacc = 0.f;
    if (tid < 288) {
      const int c3 = tid / 96, jj = tid - c3 * 96;
      const int col = c3 * 192 + 96 * half + jj;
      gacc = dotpipe<192, 576>(Wih2 + (size_t)(192 * half) * 576 + col, g2_s + 192 * half);
    }
    if (tid == 0) {
      while (aldu(fg_p) < (unsigned)(t + 1)) __builtin_amdgcn_s_sleep(1);
    }
    __syncthreads();
    // ---- F: fetch partner g half ----
    if (tid < 192) g2_s[192 * (1 - half) + tid] = aldu(gmail_p + par * 192 + tid);
    __syncthreads();

    // ---- G2: finish gi ----
    if (tid < 288) {
      const int c3 = tid / 96, jj = tid - c3 * 96;
      const int col = c3 * 192 + 96 * half + jj;
      gis[tid] = gacc + bih_s[tid]
               + dotpipe<192, 576>(Wih2 + (size_t)(192 * (1 - half)) * 576 + col,
                                   g2_s + 192 * (1 - half));
    }
    __syncthreads();

    // ---- H: GRU update (my 96 j's) ----
    if (tid < 96) {
      const int j = 96 * half + tid;
      float r = fast_sigmoid(gis[tid] + ghs[tid]);
      float z = fast_sigmoid(gis[96 + tid] + ghs[96 + tid]);
      float n = fast_tanh(gis[192 + tid] + r * ghs[192 + tid]);
      float hnew = (1.f - z) * n + z * h_f[j];
      h_f[j] = hnew;
      int trow = dir ? (TT - 1 - t) : t;
      p.out[((size_t)trow * 64 + b) * 384 + dir * 192 + j] = hnew;
    }
    __syncthreads();
    if (tid < 48) {
      unsigned pk = pack2(h_f[96 * half + 2 * tid], h_f[96 * half + 2 * tid + 1]);
      h2_s[48 * half + tid] = pk;
      astu(hmail_my + par * 48 + tid, pk);
    }
    __syncthreads();   // drain
    if (tid == 0) {
      astu(fh_my, (unsigned)(t + 1));
      while (aldu(fh_p) < (unsigned)(t + 1)) __builtin_amdgcn_s_sleep(1);
    }
    __syncthreads();
    if (tid < 48) h2_s[48 * (1 - half) + tid] = aldu(hmail_p + par * 48 + tid);
    __syncthreads();
  }
}

// ---------------- launcher ----------------
extern "C" void kernel_launch(void* const* d_in, const int* in_sizes, int n_in,
                              void* d_out, int out_size, void* d_ws, size_t ws_size,
                              hipStream_t stream) {
  (void)in_sizes; (void)n_in; (void)out_size;
  const float* memory = (const float*)d_in[0];
  const float* input  = (const float*)d_in[2];
  const float* Wm[2]  = {(const float*)d_in[3],  (const float*)d_in[12]};
  const float* Wx[2]  = {(const float*)d_in[4],  (const float*)d_in[13]};
  const float* Wh[2]  = {(const float*)d_in[5],  (const float*)d_in[14]};
  const float* v[2]   = {(const float*)d_in[6],  (const float*)d_in[15]};
  const float* Wg[2]  = {(const float*)d_in[7],  (const float*)d_in[16]};
  const float* Wih[2] = {(const float*)d_in[8],  (const float*)d_in[17]};
  const float* Whh[2] = {(const float*)d_in[9],  (const float*)d_in[18]};
  const float* bih[2] = {(const float*)d_in[10], (const float*)d_in[19]};
  const float* bhh[2] = {(const float*)d_in[11], (const float*)d_in[20]};

  char* ws = (char*)d_ws;
  const size_t OFF_FLAGS = 0;         // 4096 (3 flag arrays x 256 u32)
  const size_t OFF_EZ    = 4096;      // 2048
  const size_t OFF_GMAIL = 6144;      // 786432
  const size_t OFF_HMAIL = 792576;    // 196608
  const size_t OFF_ECTX  = 989184;    // 786432
  const size_t OFF_MPT0  = 1775616;
  const size_t OFF_MPT1  = OFF_MPT0 + 12582912;
  const size_t OFF_XP0   = OFF_MPT1 + 12582912;
  const size_t OFF_XP1   = OFF_XP0 + 12582912;
  const size_t OFF_MT    = OFF_XP1 + 12582912;
  const size_t OFF_WG0   = OFF_MT + 25165824;
  const size_t OFF_WG1   = OFF_WG0 + 1179648;
  const size_t OFF_WIH0  = OFF_WG1 + 1179648;
  const size_t OFF_WIH1  = OFF_WIH0 + 884736;
  const size_t OFF_WHH0  = OFF_WIH1 + 884736;
  const size_t OFF_WHH1  = OFF_WHH0 + 221184;
  const size_t OFF_WH0   = OFF_WHH1 + 221184;
  const size_t OFF_WH1   = OFF_WH0 + 73728;
  const size_t NEEDED    = OFF_WH1 + 73728;   // ~82 MB
  if (ws_size < NEEDED) return;

  unsigned* flags = (unsigned*)(ws + OFF_FLAGS);
  float* ez    = (float*)(ws + OFF_EZ);
  unsigned* gmail = (unsigned*)(ws + OFF_GMAIL);
  unsigned* hmail = (unsigned*)(ws + OFF_HMAIL);
  unsigned long long* ectx = (unsigned long long*)(ws + OFF_ECTX);
  __half* mpt0 = (__half*)(ws + OFF_MPT0);
  __half* mpt1 = (__half*)(ws + OFF_MPT1);
  __half* xp0  = (__half*)(ws + OFF_XP0);
  __half* xp1  = (__half*)(ws + OFF_XP1);
  __half* memt = (__half*)(ws + OFF_MT);
  unsigned* wg2[2]  = {(unsigned*)(ws + OFF_WG0),  (unsigned*)(ws + OFF_WG1)};
  unsigned* wih2[2] = {(unsigned*)(ws + OFF_WIH0), (unsigned*)(ws + OFF_WIH1)};
  unsigned* whh2[2] = {(unsigned*)(ws + OFF_WHH0), (unsigned*)(ws + OFF_WHH1)};
  unsigned* wh2[2]  = {(unsigned*)(ws + OFF_WH0),  (unsigned*)(ws + OFF_WH1)};

  hipFuncSetAttribute(reinterpret_cast<const void*>(scan_kernel),
                      hipFuncAttributeMaxDynamicSharedMemorySize, SCAN_LDS);

  hipMemsetAsync(ws + OFF_FLAGS, 0, 4096, stream);   // flags only

  ProjParams pp;
  pp.X[0] = memory; pp.W[0] = Wm[0]; pp.C[0] = mpt0; pp.rev[0] = 0; pp.transp[0] = 1;
  pp.X[1] = memory; pp.W[1] = Wm[1]; pp.C[1] = mpt1; pp.rev[1] = 0; pp.transp[1] = 1;
  pp.X[2] = input;  pp.W[2] = Wx[0]; pp.C[2] = xp0;  pp.rev[2] = 0; pp.transp[2] = 0;
  pp.X[3] = input;  pp.W[3] = Wx[1]; pp.C[3] = xp1;  pp.rev[3] = 1; pp.transp[3] = 0;
  proj_kernel<<<dim3(1024, 4), dim3(192), 0, stream>>>(pp);
  memcvt_kernel<<<dim3(MM, 64), dim3(384), 0, stream>>>(memory, memt);

  WcvtParams wp;
  for (int d = 0; d < 2; ++d) {
    wp.src[d]     = Wg[d];  wp.dst[d]     = wg2[d];  wp.tot[d]     = 384 * 768; wp.N[d]     = 768;
    wp.src[2 + d] = Wih[d]; wp.dst[2 + d] = wih2[d]; wp.tot[2 + d] = 384 * 576; wp.N[2 + d] = 576;
    wp.src[4 + d] = Whh[d]; wp.dst[4 + d] = whh2[d]; wp.tot[4 + d] = 96 * 576;  wp.N[4 + d] = 576;
    wp.src[6 + d] = Wh[d];  wp.dst[6 + d] = wh2[d];  wp.tot[6 + d] = 96 * 192;  wp.N[6 + d] = 192;
  }
  wcvt_kernel<<<dim3(288, 8), dim3(256), 0, stream>>>(wp);

  ScanParams sp;
  sp.input = input;
  sp.memt = (const unsigned*)memt;
  sp.mpt[0] = (const unsigned*)mpt0; sp.mpt[1] = (const unsigned*)mpt1;
  sp.xp[0] = xp0; sp.xp[1] = xp1;
  for (int d = 0; d < 2; ++d) {
    sp.Wh2[d] = wh2[d]; sp.Wg2[d] = wg2[d]; sp.Wih2[d] = wih2[d]; sp.Whh2[d] = whh2[d];
    sp.v[d] = v[d]; sp.bih[d] = bih[d]; sp.bhh[d] = bhh[d];
  }
  sp.ectx = ectx; sp.ez = ez; sp.gmail = gmail; sp.hmail = hmail; sp.flags = flags;
  sp.out = (float*)d_out;
  scan_kernel<<<dim3(NWG), dim3(512), SCAN_LDS, stream>>>(sp);
}